// Round 1
// baseline (6339.010 us; speedup 1.0000x reference)
//
#include <hip/hip_runtime.h>
#include <math.h>

#define NNODES 100000
#define NEDGES 1600000
#define NLAYERS 20
#define NB 8            // accumulator banks to spread atomic contention
#define BLK 256
#define GRID 1024
#define STRIDE (GRID * BLK)

// ---------------- block-wide reduce + banked f64 atomic ----------------
__device__ __forceinline__ void block_atomic_add(double v, double* addr) {
  __shared__ double sm[4];
  #pragma unroll
  for (int o = 32; o > 0; o >>= 1) v += __shfl_down(v, o, 64);
  __syncthreads();
  if ((threadIdx.x & 63) == 0) sm[threadIdx.x >> 6] = v;
  __syncthreads();
  if (threadIdx.x == 0) atomicAdd(addr, sm[0] + sm[1] + sm[2] + sm[3]);
}

// ---------------- init: pad-copy M into stride-4 buffer, zero accums ----------------
__global__ void __launch_bounds__(BLK) k_init(const float* __restrict__ Min,
                                              float* __restrict__ M,
                                              double* __restrict__ accs) {
  int tid = blockIdx.x * BLK + threadIdx.x;
  for (int v = tid; v < NNODES; v += STRIDE) {
    float4 m;
    m.x = Min[3 * v]; m.y = Min[3 * v + 1]; m.z = Min[3 * v + 2]; m.w = 0.f;
    *(float4*)(M + 4 * (size_t)v) = m;
  }
  if (blockIdx.x == 0 && threadIdx.x < 3 * NB * 8) accs[threadIdx.x] = 0.0;
}

// ---------------- K1: stats of x = e_in @ W1 + b1 ; zero Mnew & acc2 ----------------
__global__ void __launch_bounds__(BLK) k1(
    const float* __restrict__ M, const float* __restrict__ H,
    const int* __restrict__ src, const int* __restrict__ dst,
    const float* __restrict__ W1, const float* __restrict__ b1,
    float* __restrict__ Mnew, double* __restrict__ acc1, double* __restrict__ acc2) {
  int tid = blockIdx.x * BLK + threadIdx.x;
  for (int i = tid; i < NNODES * 4; i += STRIDE) Mnew[i] = 0.f;
  if (blockIdx.x == 0 && threadIdx.x < NB * 8) acc2[threadIdx.x] = 0.0;

  float sx[4] = {0, 0, 0, 0}, sq[4] = {0, 0, 0, 0};
  for (int e = tid; e < NEDGES; e += STRIDE) {
    int s = src[e], d = dst[e];
    float4 mi = *(const float4*)(M + 4 * (size_t)d);
    float4 mj = *(const float4*)(M + 4 * (size_t)s);
    size_t e3 = 3 * (size_t)e;
    float h0 = H[e3], h1 = H[e3 + 1], h2 = H[e3 + 2];
    #pragma unroll
    for (int j = 0; j < 4; ++j) {
      float x = b1[j];
      x += mi.x * W1[0 * 4 + j]; x += mi.y * W1[1 * 4 + j]; x += mi.z * W1[2 * 4 + j];
      x += mj.x * W1[3 * 4 + j]; x += mj.y * W1[4 * 4 + j]; x += mj.z * W1[5 * 4 + j];
      x += h0 * W1[6 * 4 + j];  x += h1 * W1[7 * 4 + j];  x += h2 * W1[8 * 4 + j];
      sx[j] += x; sq[j] += x * x;
    }
  }
  double* a = acc1 + (size_t)(blockIdx.x & (NB - 1)) * 8;
  #pragma unroll
  for (int j = 0; j < 4; ++j) block_atomic_add((double)sx[j], a + j);
  #pragma unroll
  for (int j = 0; j < 4; ++j) block_atomic_add((double)sq[j], a + 4 + j);
}

// ---------------- K2: Hn per edge + stats of z ; (layer19) head-BN stats ----------------
__global__ void __launch_bounds__(BLK) k2(
    const float* __restrict__ M, const float* __restrict__ H, float* __restrict__ Hn,
    const int* __restrict__ src, const int* __restrict__ dst,
    const float* __restrict__ W1, const float* __restrict__ b1,
    const float* __restrict__ g1, const float* __restrict__ be1,
    const float* __restrict__ W2, const float* __restrict__ b2,
    const float* __restrict__ V1, const float* __restrict__ vb1,
    const double* __restrict__ acc1, double* __restrict__ acc2,
    int isFinal,
    const float* __restrict__ OW1, const float* __restrict__ ob1,
    double* __restrict__ accF) {
  float s1[4], t1[4];
  {
    const double invE = 1.0 / (double)NEDGES;
    #pragma unroll
    for (int j = 0; j < 4; ++j) {
      double sx = 0.0, sq = 0.0;
      #pragma unroll
      for (int bk = 0; bk < NB; ++bk) { sx += acc1[bk * 8 + j]; sq += acc1[bk * 8 + 4 + j]; }
      double m = sx * invE;
      double var = sq * invE - m * m;
      double sc = (double)g1[j] / sqrt(var + 1e-5);
      s1[j] = (float)sc;
      t1[j] = (float)((double)be1[j] - m * sc);
    }
  }
  float sz[3] = {0, 0, 0}, szz[3] = {0, 0, 0}, sf[3] = {0, 0, 0}, sff[3] = {0, 0, 0};
  int tid = blockIdx.x * BLK + threadIdx.x;
  for (int e = tid; e < NEDGES; e += STRIDE) {
    int s = src[e], d = dst[e];
    float4 mi = *(const float4*)(M + 4 * (size_t)d);
    float4 mj = *(const float4*)(M + 4 * (size_t)s);
    size_t e3 = 3 * (size_t)e;
    float h0 = H[e3], h1 = H[e3 + 1], h2 = H[e3 + 2];
    float y[4];
    #pragma unroll
    for (int j = 0; j < 4; ++j) {
      float x = b1[j];
      x += mi.x * W1[0 * 4 + j]; x += mi.y * W1[1 * 4 + j]; x += mi.z * W1[2 * 4 + j];
      x += mj.x * W1[3 * 4 + j]; x += mj.y * W1[4 * 4 + j]; x += mj.z * W1[5 * 4 + j];
      x += h0 * W1[6 * 4 + j];  x += h1 * W1[7 * 4 + j];  x += h2 * W1[8 * 4 + j];
      y[j] = fmaxf(x * s1[j] + t1[j], 0.f);
    }
    float hn[3];
    #pragma unroll
    for (int c = 0; c < 3; ++c) {
      float v = b2[c] + y[0] * W2[0 * 3 + c] + y[1] * W2[1 * 3 + c]
                      + y[2] * W2[2 * 3 + c] + y[3] * W2[3 * 3 + c];
      hn[c] = v;
      Hn[e3 + c] = v;
    }
    #pragma unroll
    for (int c = 0; c < 3; ++c) {
      float z = vb1[c] + mi.x * V1[0 * 3 + c] + mi.y * V1[1 * 3 + c] + mi.z * V1[2 * 3 + c]
                       + hn[0] * V1[3 * 3 + c] + hn[1] * V1[4 * 3 + c] + hn[2] * V1[5 * 3 + c];
      sz[c] += z; szz[c] += z * z;
    }
    if (isFinal) {
      #pragma unroll
      for (int c = 0; c < 3; ++c) {
        float f = ob1[c] + hn[0] * OW1[0 * 3 + c] + hn[1] * OW1[1 * 3 + c] + hn[2] * OW1[2 * 3 + c];
        sf[c] += f; sff[c] += f * f;
      }
    }
  }
  double* a2 = acc2 + (size_t)(blockIdx.x & (NB - 1)) * 8;
  #pragma unroll
  for (int c = 0; c < 3; ++c) block_atomic_add((double)sz[c], a2 + c);
  #pragma unroll
  for (int c = 0; c < 3; ++c) block_atomic_add((double)szz[c], a2 + 3 + c);
  if (isFinal) {
    double* af = accF + (size_t)(blockIdx.x & (NB - 1)) * 8;
    #pragma unroll
    for (int c = 0; c < 3; ++c) block_atomic_add((double)sf[c], af + c);
    #pragma unroll
    for (int c = 0; c < 3; ++c) block_atomic_add((double)sff[c], af + 3 + c);
  }
}

// ---------------- K3: messages + scatter-add into Mnew ; zero acc1 for next layer ----
__global__ void __launch_bounds__(BLK) k3(
    const float* __restrict__ M, const float* __restrict__ Hn,
    const int* __restrict__ dst,
    const float* __restrict__ V1, const float* __restrict__ vb1,
    const float* __restrict__ vg1, const float* __restrict__ vbe1,
    const float* __restrict__ V2, const float* __restrict__ vb2,
    const double* __restrict__ acc2, double* __restrict__ acc1,
    float* __restrict__ Mnew) {
  float s2[3], t2[3];
  {
    const double invE = 1.0 / (double)NEDGES;
    #pragma unroll
    for (int c = 0; c < 3; ++c) {
      double sz = 0.0, sq = 0.0;
      #pragma unroll
      for (int bk = 0; bk < NB; ++bk) { sz += acc2[bk * 8 + c]; sq += acc2[bk * 8 + 3 + c]; }
      double m = sz * invE;
      double var = sq * invE - m * m;
      double sc = (double)vg1[c] / sqrt(var + 1e-5);
      s2[c] = (float)sc;
      t2[c] = (float)((double)vbe1[c] - m * sc);
    }
  }
  if (blockIdx.x == 0 && threadIdx.x < NB * 8) acc1[threadIdx.x] = 0.0;
  int tid = blockIdx.x * BLK + threadIdx.x;
  for (int e = tid; e < NEDGES; e += STRIDE) {
    int d = dst[e];
    float4 mi = *(const float4*)(M + 4 * (size_t)d);
    size_t e3 = 3 * (size_t)e;
    float h0 = Hn[e3], h1 = Hn[e3 + 1], h2 = Hn[e3 + 2];
    float y[3];
    #pragma unroll
    for (int c = 0; c < 3; ++c) {
      float z = vb1[c] + mi.x * V1[0 * 3 + c] + mi.y * V1[1 * 3 + c] + mi.z * V1[2 * 3 + c]
                       + h0 * V1[3 * 3 + c] + h1 * V1[4 * 3 + c] + h2 * V1[5 * 3 + c];
      y[c] = fmaxf(z * s2[c] + t2[c], 0.f);
    }
    #pragma unroll
    for (int c = 0; c < 3; ++c) {
      float msg = vb2[c] + y[0] * V2[0 * 3 + c] + y[1] * V2[1 * 3 + c] + y[2] * V2[2 * 3 + c];
      atomicAdd(Mnew + 4 * (size_t)d + c, msg);
    }
  }
}

// ---------------- head: BN + ReLU + Linear(3,2) + softmax ----------------
__global__ void __launch_bounds__(BLK) f2(
    const float* __restrict__ H,
    const float* __restrict__ OW1, const float* __restrict__ ob1,
    const float* __restrict__ og, const float* __restrict__ obe,
    const float* __restrict__ OW2, const float* __restrict__ ob2,
    const double* __restrict__ accF, float* __restrict__ out) {
  float sF[3], tF[3];
  {
    const double invE = 1.0 / (double)NEDGES;
    #pragma unroll
    for (int c = 0; c < 3; ++c) {
      double sx = 0.0, sq = 0.0;
      #pragma unroll
      for (int bk = 0; bk < NB; ++bk) { sx += accF[bk * 8 + c]; sq += accF[bk * 8 + 3 + c]; }
      double m = sx * invE;
      double var = sq * invE - m * m;
      double sc = (double)og[c] / sqrt(var + 1e-5);
      sF[c] = (float)sc;
      tF[c] = (float)((double)obe[c] - m * sc);
    }
  }
  int tid = blockIdx.x * BLK + threadIdx.x;
  for (int e = tid; e < NEDGES; e += STRIDE) {
    size_t e3 = 3 * (size_t)e;
    float h0 = H[e3], h1 = H[e3 + 1], h2 = H[e3 + 2];
    float y[3];
    #pragma unroll
    for (int c = 0; c < 3; ++c) {
      float f = ob1[c] + h0 * OW1[0 * 3 + c] + h1 * OW1[1 * 3 + c] + h2 * OW1[2 * 3 + c];
      y[c] = fmaxf(f * sF[c] + tF[c], 0.f);
    }
    float l0 = ob2[0] + y[0] * OW2[0] + y[1] * OW2[2] + y[2] * OW2[4];
    float l1 = ob2[1] + y[0] * OW2[1] + y[1] * OW2[3] + y[2] * OW2[5];
    float mx = fmaxf(l0, l1);
    float e0 = __expf(l0 - mx), e1 = __expf(l1 - mx);
    float inv = 1.f / (e0 + e1);
    float2 o; o.x = e0 * inv; o.y = e1 * inv;
    *(float2*)(out + 2 * (size_t)e) = o;
  }
}

extern "C" void kernel_launch(void* const* d_in, const int* in_sizes, int n_in,
                              void* d_out, int out_size, void* d_ws, size_t ws_size,
                              hipStream_t stream) {
  const float* M_in   = (const float*)d_in[0];
  const float* H_in   = (const float*)d_in[1];
  const int*   ei     = (const int*)d_in[2];
  const float* we_w1  = (const float*)d_in[3];
  const float* we_b1  = (const float*)d_in[4];
  const float* we_g1  = (const float*)d_in[5];
  const float* we_be1 = (const float*)d_in[6];
  const float* we_w2  = (const float*)d_in[7];
  const float* we_b2  = (const float*)d_in[8];
  const float* wv_w1  = (const float*)d_in[9];
  const float* wv_b1  = (const float*)d_in[10];
  const float* wv_g1  = (const float*)d_in[11];
  const float* wv_be1 = (const float*)d_in[12];
  const float* wv_w2  = (const float*)d_in[13];
  const float* wv_b2  = (const float*)d_in[14];
  const float* out_w1 = (const float*)d_in[15];
  const float* out_b1 = (const float*)d_in[16];
  const float* out_g  = (const float*)d_in[17];
  const float* out_be = (const float*)d_in[18];
  const float* out_w2 = (const float*)d_in[19];
  const float* out_b2 = (const float*)d_in[20];
  const int* src = ei;
  const int* dst = ei + NEDGES;

  float* ws = (float*)d_ws;
  float* MA = ws;                       // N*4 floats, padded stride 4
  float* MB = ws + 400000;
  float* H0 = ws + 800000;              // E*3 floats
  float* H1 = ws + 5600000;
  double* accs = (double*)(ws + 10400000);  // byte offset 41.6e6, 8B-aligned
  double* acc1 = accs;
  double* acc2 = accs + NB * 8;
  double* accF = accs + 2 * NB * 8;

  k_init<<<GRID, BLK, 0, stream>>>(M_in, MA, accs);
  for (int l = 0; l < NLAYERS; ++l) {
    const float* Mc = (l & 1) ? MB : MA;
    float*       Mn = (l & 1) ? MA : MB;
    const float* Hc = (l == 0) ? H_in : ((l & 1) ? H0 : H1);
    float*       Hw = (l & 1) ? H1 : H0;
    k1<<<GRID, BLK, 0, stream>>>(Mc, Hc, src, dst, we_w1, we_b1, Mn, acc1, acc2);
    k2<<<GRID, BLK, 0, stream>>>(Mc, Hc, Hw, src, dst, we_w1, we_b1, we_g1, we_be1,
                                 we_w2, we_b2, wv_w1, wv_b1, acc1, acc2,
                                 (l == NLAYERS - 1) ? 1 : 0, out_w1, out_b1, accF);
    if (l < NLAYERS - 1)
      k3<<<GRID, BLK, 0, stream>>>(Mc, Hw, dst, wv_w1, wv_b1, wv_g1, wv_be1,
                                   wv_w2, wv_b2, acc2, acc1, Mn);
  }
  f2<<<GRID, BLK, 0, stream>>>(H1, out_w1, out_b1, out_g, out_be, out_w2, out_b2,
                               accF, (float*)d_out);
}

// Round 2
// 2187.395 us; speedup vs baseline: 2.8980x; 2.8980x over previous
//
#include <hip/hip_runtime.h>
#include <math.h>

#define NNODES 100000
#define NEDGES 1600000
#define NLAYERS 20
#define NB 8            // accumulator banks to spread atomic contention
#define BLK 256
#define GRIDE 1024      // edge-parallel kernels
#define STRIDE (GRIDE * BLK)

// ---------------- block-wide reduce + banked f64 atomic ----------------
__device__ __forceinline__ void block_atomic_add(double v, double* addr) {
  __shared__ double sm[4];
  #pragma unroll
  for (int o = 32; o > 0; o >>= 1) v += __shfl_down(v, o, 64);
  __syncthreads();
  if ((threadIdx.x & 63) == 0) sm[threadIdx.x >> 6] = v;
  __syncthreads();
  if (threadIdx.x == 0) atomicAdd(addr, sm[0] + sm[1] + sm[2] + sm[3]);
}

// ---------------- kz: pad-copy M, zero hist + accums ----------------
__global__ void __launch_bounds__(BLK) kz(const float* __restrict__ Min,
                                          float* __restrict__ M,
                                          int* __restrict__ hist,
                                          double* __restrict__ accs) {
  int tid = blockIdx.x * BLK + threadIdx.x;
  for (int v = tid; v < NNODES; v += STRIDE) {
    float4 m;
    m.x = Min[3 * v]; m.y = Min[3 * v + 1]; m.z = Min[3 * v + 2]; m.w = 0.f;
    *(float4*)(M + 4 * (size_t)v) = m;
    hist[v] = 0;
  }
  if (blockIdx.x == 0 && threadIdx.x < 3 * NB * 8) accs[threadIdx.x] = 0.0;
}

// ---------------- kh: histogram of dst ----------------
__global__ void __launch_bounds__(BLK) kh(const int* __restrict__ dst,
                                          int* __restrict__ hist) {
  int tid = blockIdx.x * BLK + threadIdx.x;
  for (int e = tid; e < NEDGES; e += STRIDE) atomicAdd(&hist[dst[e]], 1);
}

// ---------------- ks: exclusive scan (1 block, 1024 thr) -> off, cursor ----
#define SCN 1024
#define SCHUNK 98   // 98*1024 >= 100000
__global__ void __launch_bounds__(SCN) ks(const int* __restrict__ hist,
                                          int* __restrict__ off,
                                          int* __restrict__ cursor) {
  __shared__ int part[SCN];
  int t = threadIdx.x;
  int base = t * SCHUNK;
  int s = 0;
  for (int i = 0; i < SCHUNK; ++i) {
    int idx = base + i;
    if (idx < NNODES) s += hist[idx];
  }
  part[t] = s;
  __syncthreads();
  for (int o = 1; o < SCN; o <<= 1) {
    int v = (t >= o) ? part[t - o] : 0;
    __syncthreads();
    part[t] += v;
    __syncthreads();
  }
  int run = (t == 0) ? 0 : part[t - 1];
  for (int i = 0; i < SCHUNK; ++i) {
    int idx = base + i;
    if (idx < NNODES) {
      off[idx] = run; cursor[idx] = run;
      run += hist[idx];
    }
  }
  if (t == SCN - 1) off[NNODES] = run;
}

// ---------------- kp: scatter into CSR order; permute H ----------------
__global__ void __launch_bounds__(BLK) kp(const int* __restrict__ src,
                                          const int* __restrict__ dst,
                                          const float* __restrict__ Hin,
                                          int* __restrict__ cursor,
                                          int* __restrict__ sp,
                                          int* __restrict__ dp,
                                          int* __restrict__ pos,
                                          float* __restrict__ Hp) {
  int tid = blockIdx.x * BLK + threadIdx.x;
  for (int e = tid; e < NEDGES; e += STRIDE) {
    int d = dst[e];
    int p = atomicAdd(&cursor[d], 1);
    sp[p] = src[e];
    dp[p] = d;
    pos[e] = p;
    size_t e3 = 3 * (size_t)e, p3 = 3 * (size_t)p;
    Hp[p3] = Hin[e3]; Hp[p3 + 1] = Hin[e3 + 1]; Hp[p3 + 2] = Hin[e3 + 2];
  }
}

// ---------------- K1: stats of x = e_in @ W1 + b1 ; zero acc2 ----------------
__global__ void __launch_bounds__(BLK) k1(
    const float* __restrict__ M, const float* __restrict__ H,
    const int* __restrict__ sp, const int* __restrict__ dp,
    const float* __restrict__ W1, const float* __restrict__ b1,
    double* __restrict__ acc1, double* __restrict__ acc2) {
  int tid = blockIdx.x * BLK + threadIdx.x;
  if (blockIdx.x == 0 && threadIdx.x < NB * 8) acc2[threadIdx.x] = 0.0;

  float sx[4] = {0, 0, 0, 0}, sq[4] = {0, 0, 0, 0};
  for (int e = tid; e < NEDGES; e += STRIDE) {
    int s = sp[e], d = dp[e];
    float4 mi = *(const float4*)(M + 4 * (size_t)d);
    float4 mj = *(const float4*)(M + 4 * (size_t)s);
    size_t e3 = 3 * (size_t)e;
    float h0 = H[e3], h1 = H[e3 + 1], h2 = H[e3 + 2];
    #pragma unroll
    for (int j = 0; j < 4; ++j) {
      float x = b1[j];
      x += mi.x * W1[0 * 4 + j]; x += mi.y * W1[1 * 4 + j]; x += mi.z * W1[2 * 4 + j];
      x += mj.x * W1[3 * 4 + j]; x += mj.y * W1[4 * 4 + j]; x += mj.z * W1[5 * 4 + j];
      x += h0 * W1[6 * 4 + j];  x += h1 * W1[7 * 4 + j];  x += h2 * W1[8 * 4 + j];
      sx[j] += x; sq[j] += x * x;
    }
  }
  double* a = acc1 + (size_t)(blockIdx.x & (NB - 1)) * 8;
  #pragma unroll
  for (int j = 0; j < 4; ++j) block_atomic_add((double)sx[j], a + j);
  #pragma unroll
  for (int j = 0; j < 4; ++j) block_atomic_add((double)sq[j], a + 4 + j);
}

// ---------------- K2: Hn per edge + stats of z ; (layer19) head-BN stats ----
__global__ void __launch_bounds__(BLK) k2(
    const float* __restrict__ M, const float* __restrict__ H, float* __restrict__ Hn,
    const int* __restrict__ sp, const int* __restrict__ dp,
    const float* __restrict__ W1, const float* __restrict__ b1,
    const float* __restrict__ g1, const float* __restrict__ be1,
    const float* __restrict__ W2, const float* __restrict__ b2,
    const float* __restrict__ V1, const float* __restrict__ vb1,
    const double* __restrict__ acc1, double* __restrict__ acc2,
    int isFinal,
    const float* __restrict__ OW1, const float* __restrict__ ob1,
    double* __restrict__ accF) {
  float s1[4], t1[4];
  {
    const double invE = 1.0 / (double)NEDGES;
    #pragma unroll
    for (int j = 0; j < 4; ++j) {
      double sx = 0.0, sq = 0.0;
      #pragma unroll
      for (int bk = 0; bk < NB; ++bk) { sx += acc1[bk * 8 + j]; sq += acc1[bk * 8 + 4 + j]; }
      double m = sx * invE;
      double var = sq * invE - m * m;
      double sc = (double)g1[j] / sqrt(var + 1e-5);
      s1[j] = (float)sc;
      t1[j] = (float)((double)be1[j] - m * sc);
    }
  }
  float sz[3] = {0, 0, 0}, szz[3] = {0, 0, 0}, sf[3] = {0, 0, 0}, sff[3] = {0, 0, 0};
  int tid = blockIdx.x * BLK + threadIdx.x;
  for (int e = tid; e < NEDGES; e += STRIDE) {
    int s = sp[e], d = dp[e];
    float4 mi = *(const float4*)(M + 4 * (size_t)d);
    float4 mj = *(const float4*)(M + 4 * (size_t)s);
    size_t e3 = 3 * (size_t)e;
    float h0 = H[e3], h1 = H[e3 + 1], h2 = H[e3 + 2];
    float y[4];
    #pragma unroll
    for (int j = 0; j < 4; ++j) {
      float x = b1[j];
      x += mi.x * W1[0 * 4 + j]; x += mi.y * W1[1 * 4 + j]; x += mi.z * W1[2 * 4 + j];
      x += mj.x * W1[3 * 4 + j]; x += mj.y * W1[4 * 4 + j]; x += mj.z * W1[5 * 4 + j];
      x += h0 * W1[6 * 4 + j];  x += h1 * W1[7 * 4 + j];  x += h2 * W1[8 * 4 + j];
      y[j] = fmaxf(x * s1[j] + t1[j], 0.f);
    }
    float hn[3];
    #pragma unroll
    for (int c = 0; c < 3; ++c) {
      float v = b2[c] + y[0] * W2[0 * 3 + c] + y[1] * W2[1 * 3 + c]
                      + y[2] * W2[2 * 3 + c] + y[3] * W2[3 * 3 + c];
      hn[c] = v;
      Hn[e3 + c] = v;
    }
    #pragma unroll
    for (int c = 0; c < 3; ++c) {
      float z = vb1[c] + mi.x * V1[0 * 3 + c] + mi.y * V1[1 * 3 + c] + mi.z * V1[2 * 3 + c]
                       + hn[0] * V1[3 * 3 + c] + hn[1] * V1[4 * 3 + c] + hn[2] * V1[5 * 3 + c];
      sz[c] += z; szz[c] += z * z;
    }
    if (isFinal) {
      #pragma unroll
      for (int c = 0; c < 3; ++c) {
        float f = ob1[c] + hn[0] * OW1[0 * 3 + c] + hn[1] * OW1[1 * 3 + c] + hn[2] * OW1[2 * 3 + c];
        sf[c] += f; sff[c] += f * f;
      }
    }
  }
  double* a2 = acc2 + (size_t)(blockIdx.x & (NB - 1)) * 8;
  #pragma unroll
  for (int c = 0; c < 3; ++c) block_atomic_add((double)sz[c], a2 + c);
  #pragma unroll
  for (int c = 0; c < 3; ++c) block_atomic_add((double)szz[c], a2 + 3 + c);
  if (isFinal) {
    double* af = accF + (size_t)(blockIdx.x & (NB - 1)) * 8;
    #pragma unroll
    for (int c = 0; c < 3; ++c) block_atomic_add((double)sf[c], af + c);
    #pragma unroll
    for (int c = 0; c < 3; ++c) block_atomic_add((double)sff[c], af + 3 + c);
  }
}

// ---------------- K3: node-centric aggregation via CSR; zero acc1 ----------
__global__ void __launch_bounds__(BLK) k3(
    const float* __restrict__ M, const float* __restrict__ Hn,
    const int* __restrict__ off,
    const float* __restrict__ V1, const float* __restrict__ vb1,
    const float* __restrict__ vg1, const float* __restrict__ vbe1,
    const float* __restrict__ V2, const float* __restrict__ vb2,
    const double* __restrict__ acc2, double* __restrict__ acc1,
    float* __restrict__ Mnew) {
  float s2[3], t2[3];
  {
    const double invE = 1.0 / (double)NEDGES;
    #pragma unroll
    for (int c = 0; c < 3; ++c) {
      double sz = 0.0, sq = 0.0;
      #pragma unroll
      for (int bk = 0; bk < NB; ++bk) { sz += acc2[bk * 8 + c]; sq += acc2[bk * 8 + 3 + c]; }
      double m = sz * invE;
      double var = sq * invE - m * m;
      double sc = (double)vg1[c] / sqrt(var + 1e-5);
      s2[c] = (float)sc;
      t2[c] = (float)((double)vbe1[c] - m * sc);
    }
  }
  if (blockIdx.x == 0 && threadIdx.x < NB * 8) acc1[threadIdx.x] = 0.0;

  int v = blockIdx.x * BLK + threadIdx.x;
  if (v >= NNODES) return;
  float4 mi = *(const float4*)(M + 4 * (size_t)v);
  int e0 = off[v], e1 = off[v + 1];
  float a0 = 0.f, a1 = 0.f, a2v = 0.f;
  for (int e = e0; e < e1; ++e) {
    size_t e3 = 3 * (size_t)e;
    float h0 = Hn[e3], h1 = Hn[e3 + 1], h2 = Hn[e3 + 2];
    float y[3];
    #pragma unroll
    for (int c = 0; c < 3; ++c) {
      float z = vb1[c] + mi.x * V1[0 * 3 + c] + mi.y * V1[1 * 3 + c] + mi.z * V1[2 * 3 + c]
                       + h0 * V1[3 * 3 + c] + h1 * V1[4 * 3 + c] + h2 * V1[5 * 3 + c];
      y[c] = fmaxf(z * s2[c] + t2[c], 0.f);
    }
    a0 += vb2[0] + y[0] * V2[0] + y[1] * V2[3] + y[2] * V2[6];
    a1 += vb2[1] + y[0] * V2[1] + y[1] * V2[4] + y[2] * V2[7];
    a2v += vb2[2] + y[0] * V2[2] + y[1] * V2[5] + y[2] * V2[8];
  }
  float4 o; o.x = a0; o.y = a1; o.z = a2v; o.w = 0.f;
  *(float4*)(Mnew + 4 * (size_t)v) = o;
}

// ---------------- head: BN + ReLU + Linear(3,2) + softmax (un-permute) ----
__global__ void __launch_bounds__(BLK) f2(
    const float* __restrict__ H, const int* __restrict__ pos,
    const float* __restrict__ OW1, const float* __restrict__ ob1,
    const float* __restrict__ og, const float* __restrict__ obe,
    const float* __restrict__ OW2, const float* __restrict__ ob2,
    const double* __restrict__ accF, float* __restrict__ out) {
  float sF[3], tF[3];
  {
    const double invE = 1.0 / (double)NEDGES;
    #pragma unroll
    for (int c = 0; c < 3; ++c) {
      double sx = 0.0, sq = 0.0;
      #pragma unroll
      for (int bk = 0; bk < NB; ++bk) { sx += accF[bk * 8 + c]; sq += accF[bk * 8 + 3 + c]; }
      double m = sx * invE;
      double var = sq * invE - m * m;
      double sc = (double)og[c] / sqrt(var + 1e-5);
      sF[c] = (float)sc;
      tF[c] = (float)((double)obe[c] - m * sc);
    }
  }
  int tid = blockIdx.x * BLK + threadIdx.x;
  for (int e = tid; e < NEDGES; e += STRIDE) {
    size_t p3 = 3 * (size_t)pos[e];
    float h0 = H[p3], h1 = H[p3 + 1], h2 = H[p3 + 2];
    float y[3];
    #pragma unroll
    for (int c = 0; c < 3; ++c) {
      float f = ob1[c] + h0 * OW1[0 * 3 + c] + h1 * OW1[1 * 3 + c] + h2 * OW1[2 * 3 + c];
      y[c] = fmaxf(f * sF[c] + tF[c], 0.f);
    }
    float l0 = ob2[0] + y[0] * OW2[0] + y[1] * OW2[2] + y[2] * OW2[4];
    float l1 = ob2[1] + y[0] * OW2[1] + y[1] * OW2[3] + y[2] * OW2[5];
    float mx = fmaxf(l0, l1);
    float e0 = __expf(l0 - mx), e1 = __expf(l1 - mx);
    float inv = 1.f / (e0 + e1);
    float2 o; o.x = e0 * inv; o.y = e1 * inv;
    *(float2*)(out + 2 * (size_t)e) = o;
  }
}

extern "C" void kernel_launch(void* const* d_in, const int* in_sizes, int n_in,
                              void* d_out, int out_size, void* d_ws, size_t ws_size,
                              hipStream_t stream) {
  const float* M_in   = (const float*)d_in[0];
  const float* H_in   = (const float*)d_in[1];
  const int*   ei     = (const int*)d_in[2];
  const float* we_w1  = (const float*)d_in[3];
  const float* we_b1  = (const float*)d_in[4];
  const float* we_g1  = (const float*)d_in[5];
  const float* we_be1 = (const float*)d_in[6];
  const float* we_w2  = (const float*)d_in[7];
  const float* we_b2  = (const float*)d_in[8];
  const float* wv_w1  = (const float*)d_in[9];
  const float* wv_b1  = (const float*)d_in[10];
  const float* wv_g1  = (const float*)d_in[11];
  const float* wv_be1 = (const float*)d_in[12];
  const float* wv_w2  = (const float*)d_in[13];
  const float* wv_b2  = (const float*)d_in[14];
  const float* out_w1 = (const float*)d_in[15];
  const float* out_b1 = (const float*)d_in[16];
  const float* out_g  = (const float*)d_in[17];
  const float* out_be = (const float*)d_in[18];
  const float* out_w2 = (const float*)d_in[19];
  const float* out_b2 = (const float*)d_in[20];
  const int* src = ei;
  const int* dst = ei + NEDGES;

  float* ws = (float*)d_ws;
  float* MA  = ws;                         // N*4
  float* MB  = ws + 400000;                // N*4
  float* Hp0 = ws + 800000;                // E*3
  float* Hp1 = ws + 5600000;               // E*3
  int* ib     = (int*)(ws + 10400000);
  int* sp     = ib;                        // E
  int* dp     = ib + 1600000;              // E
  int* pos    = ib + 3200000;              // E
  int* hist   = ib + 4800000;              // N
  int* off    = ib + 4900000;              // N+1
  int* cursor = ib + 5000001;              // N
  double* accs = (double*)(ws + 10400000 + 5100002);  // 8B-aligned
  double* acc1 = accs;
  double* acc2 = accs + NB * 8;
  double* accF = accs + 2 * NB * 8;

  // --- build CSR permutation (same every call; dst is a static input) ---
  kz<<<GRIDE, BLK, 0, stream>>>(M_in, MA, hist, accs);
  kh<<<GRIDE, BLK, 0, stream>>>(dst, hist);
  ks<<<1, SCN, 0, stream>>>(hist, off, cursor);
  kp<<<GRIDE, BLK, 0, stream>>>(src, dst, H_in, cursor, sp, dp, pos, Hp0);

  for (int l = 0; l < NLAYERS; ++l) {
    const float* Mc = (l & 1) ? MB : MA;
    float*       Mn = (l & 1) ? MA : MB;
    const float* Hc = (l & 1) ? Hp1 : Hp0;
    float*       Hw = (l & 1) ? Hp0 : Hp1;
    k1<<<GRIDE, BLK, 0, stream>>>(Mc, Hc, sp, dp, we_w1, we_b1, acc1, acc2);
    k2<<<GRIDE, BLK, 0, stream>>>(Mc, Hc, Hw, sp, dp, we_w1, we_b1, we_g1, we_be1,
                                  we_w2, we_b2, wv_w1, wv_b1, acc1, acc2,
                                  (l == NLAYERS - 1) ? 1 : 0, out_w1, out_b1, accF);
    if (l < NLAYERS - 1)
      k3<<<(NNODES + BLK - 1) / BLK, BLK, 0, stream>>>(
          Mc, Hw, off, wv_w1, wv_b1, wv_g1, wv_be1, wv_w2, wv_b2, acc2, acc1, Mn);
  }
  // final Hn lives in Hp0 (layer 19 wrote Hw = Hp0)
  f2<<<GRIDE, BLK, 0, stream>>>(Hp0, pos, out_w1, out_b1, out_g, out_be,
                                out_w2, out_b2, accF, (float*)d_out);
}